// Round 11
// baseline (195.869 us; speedup 1.0000x reference)
//
#include <hip/hip_runtime.h>
#include <math.h>

#define Lc 13
#define Hc 1024
#define Bc 32
#define Sc 2048
#define BSc (Bc*Sc)
#define CHUNK 128
#define NCHUNK 16
#define NBLK (Bc*NCHUNK)   // 512 chunk blocks

#define INV_LN2 1.44269504088896340736f
#define LN2f    0.69314718055994530942f

#if __has_builtin(__builtin_amdgcn_exp2f)
#define EXP2F(x) __builtin_amdgcn_exp2f(x)
#else
#define EXP2F(x) exp2f(x)
#endif
#if __has_builtin(__builtin_amdgcn_logf)
#define LOG2F(x) __builtin_amdgcn_logf(x)
#else
#define LOG2F(x) log2f(x)
#endif

// DPP-based partial butterfly: v += lane-permuted v (VALU only, no LDS).
template <int CTRL>
__device__ __forceinline__ float dpp_add(float v) {
  int p = __builtin_amdgcn_update_dpp(0, __float_as_int(v), CTRL, 0xF, 0xF, true);
  return v + __int_as_float(p);
}

// ---------------------------------------------------------------------------
// Kernel A: logits = hs @ W^T + b.  NO LDS (W is 53KB -> L1/L2-resident;
// guide CM#7: don't stage what cache-fits). Lane = rin*16+ch covers row
// rowBase+rin, 16B h-chunk ch of each 64-float slice kk (16 slices = full
// 1024 h, R9 bug fixed in R10). Per slice: 1 A-load (HBM stream, depth-2
// register prefetch) + 13 W dwordx4 (L1/L2 broadcast, 4-way lane alias) +
// 52 FMA. Reduction within 16-lane groups = pure DPP (validated R7-R10).
// 256 thr / 4 waves / 16 rows per block, grid 4096; (256,8) -> 32 waves/CU,
// ~45 VGPR (under the 64 cap -- no spill, R6 lesson), zero barriers.
// ---------------------------------------------------------------------------
__global__ __launch_bounds__(256, 8)
void k_logits(const float* __restrict__ A, const float* __restrict__ W,
              const float* __restrict__ bias, float* __restrict__ out) {
  const int tid = threadIdx.x;
  const int ln  = tid & 63;
  const int wv  = tid >> 6;            // 0..3
  const int rin = ln >> 4;             // row within wave's 4-row group
  const int ch  = ln & 15;             // 16B chunk within 64-float slice
  const size_t row = (size_t)blockIdx.x * 16 + (size_t)wv * 4 + rin;

  const float* Ar = A + row * (size_t)Hc + ch * 4;
  const float* Wb = W + ch * 4;

  // depth-2 register prefetch of the A stream (3 rotating named slots)
  float4 s0 = *(const float4*)(Ar);
  float4 s1 = *(const float4*)(Ar + 64);
  float4 s2;

  float acc[Lc];
#pragma unroll
  for (int l = 0; l < Lc; ++l) acc[l] = 0.f;

#pragma unroll
  for (int kk = 0; kk < 16; ++kk) {
    // consume slot kk%3 (static under full unroll)
    float4 a = (kk % 3 == 0) ? s0 : (kk % 3 == 1) ? s1 : s2;
    // issue slice kk+2 into slot (kk+2)%3 BEFORE the W loads of this slice
    if (kk + 2 < 16) {
      float4 n = *(const float4*)(Ar + (kk + 2) * 64);
      if ((kk + 2) % 3 == 0)      s0 = n;
      else if ((kk + 2) % 3 == 1) s1 = n;
      else                        s2 = n;
    }
    const float* wb = Wb + kk * 64;
#pragma unroll
    for (int l = 0; l < Lc; ++l) {
      float4 w = *(const float4*)(wb + l * Hc);   // L1/L2 hit, 4-way broadcast
      acc[l] = fmaf(a.x, w.x, acc[l]); acc[l] = fmaf(a.y, w.y, acc[l]);
      acc[l] = fmaf(a.z, w.z, acc[l]); acc[l] = fmaf(a.w, w.w, acc[l]);
    }
  }

  // reduce within 16-lane group: xor1,xor2 (quad_perm), ^7, ^15 (mirrors)
#pragma unroll
  for (int l = 0; l < Lc; ++l) {
    float s = acc[l];
    s = dpp_add<0xB1>(s);
    s = dpp_add<0x4E>(s);
    s = dpp_add<0x141>(s);
    s = dpp_add<0x140>(s);
    acc[l] = s;
  }
  float ov = 0.f;
#pragma unroll
  for (int l = 0; l < Lc; ++l) ov = (ch == l) ? acc[l] + bias[l] : ov;
  if (ch < Lc) out[row * Lc + ch] = ov;
}

// ---------------------------------------------------------------------------
// Kernel B: per (batch, chunk) 13x13 transfer matrix, LINEAR domain
// (13 shfl + 13 fma + 1 exp2 per step; exponent-extract renorm every 8).
// Wave 0 also computes the chunk's numerator partial. Block 0 zeroes out0.
// ---------------------------------------------------------------------------
__global__ void k_chunks(const float* __restrict__ logits, const int* __restrict__ mask,
                         const int* __restrict__ labels, const float* __restrict__ T,
                         float* __restrict__ Mout, float* __restrict__ numpart,
                         float* __restrict__ cntpart, float* __restrict__ out0) {
  const int bp = blockIdx.x;
  const int b  = bp >> 4;       // NCHUNK == 16
  const int p  = bp & 15;
  const int tid = threadIdx.x;
  if (bp == 0 && tid == 0) out0[0] = 0.f;   // zero loss accumulator for k_final
  const int g = tid >> 4;
  const int k = tid & 15;
  const int kk = (k < 13) ? k : 0;
  const int gg = (g < 13) ? g : 0;
  const bool active = (g < 13) && (k < 13);
  const size_t lbase = (size_t)b * Sc;
  const int t0 = 1 + p * CHUNK;
  const int t1 = min(t0 + CHUNK, Sc);

  float U[13];   // column kk of exp(T)
#pragma unroll
  for (int j = 0; j < 13; ++j) U[j] = EXP2F(T[j * 13 + kk] * INV_LN2);

  float e0 = logits[(lbase + t0) * Lc + kk] * INV_LN2;
  int   m0 = mask[lbase + t0];
  float P = m0 ? EXP2F(T[gg * 13 + kk] * INV_LN2 + e0) : ((g == k) ? 1.f : 0.f);
  float off = 0.f;

  for (int t = t0 + 1; t < t1; ++t) {
    float e2 = logits[(lbase + t) * Lc + kk] * INV_LN2;
    int   mk = mask[lbase + t];
    float pj[13];
#pragma unroll
    for (int j = 0; j < 13; ++j) pj[j] = __shfl(P, j, 16);
    float s0 = pj[0] * U[0];  s0 = fmaf(pj[4],  U[4],  s0);
    s0 = fmaf(pj[8],  U[8],  s0);  s0 = fmaf(pj[12], U[12], s0);
    float s1 = pj[1] * U[1];  s1 = fmaf(pj[5],  U[5],  s1);  s1 = fmaf(pj[9],  U[9],  s1);
    float s2 = pj[2] * U[2];  s2 = fmaf(pj[6],  U[6],  s2);  s2 = fmaf(pj[10], U[10], s2);
    float s3 = pj[3] * U[3];  s3 = fmaf(pj[7],  U[7],  s3);  s3 = fmaf(pj[11], U[11], s3);
    float s = (s0 + s1) + (s2 + s3);
    float Pn = EXP2F(e2) * s;
    P = mk ? Pn : P;
    if (((t - t0) & 7) == 0) {   // renorm: keep row max in [1,2)
      float mx = P;
#pragma unroll
      for (int o = 1; o < 16; o <<= 1) mx = fmaxf(mx, __shfl_xor(mx, o, 16));
      unsigned eb = (__float_as_uint(mx) >> 23) & 255u;
      float scale = __uint_as_float((254u - eb) << 23);   // 2^(127-eb)
      P *= scale;
      off += (float)((int)eb - 127);
    }
  }
  if (active) Mout[(size_t)bp * 169 + g * 13 + k] = (P > 0.f) ? (LOG2F(P) + off) : -1e30f;

  // ---- numerator partial for this chunk's tokens [t0, t1) ----
  if (tid < 64) {
    float np = 0.f; int cnt = 0;
    for (int t = t0 + tid; t < t1; t += 64) {
      int mk = mask[lbase + t];
      if (mk) {
        int tg = labels[lbase + t];
        int pg = labels[lbase + t - 1];
        np += T[pg * 13 + tg] + logits[(lbase + t) * Lc + tg];
        cnt += 1;
      }
    }
#pragma unroll
    for (int o = 1; o < 64; o <<= 1) {
      np  += __shfl_xor(np, o, 64);
      cnt += __shfl_xor(cnt, o, 64);
    }
    if (tid == 0) { numpart[bp] = np; cntpart[bp] = (float)cnt; }
  }
}

// ---------------------------------------------------------------------------
// Kernel C: per batch: combine 16 chunk matrices (log2 domain) -> denominator;
// assemble numerator from partials; atomicAdd loss.
// ---------------------------------------------------------------------------
__global__ void k_final(const float* __restrict__ logits, const int* __restrict__ mask,
                        const int* __restrict__ labels, const float* __restrict__ startT,
                        const float* __restrict__ endT, const float* __restrict__ Mws,
                        const float* __restrict__ numpart, const float* __restrict__ cntpart,
                        float* __restrict__ out0) {
  const int b = blockIdx.x;
  const int lane = threadIdx.x;
  const int kk = (lane < 13) ? lane : 0;
  const size_t lbase = (size_t)b * Sc;

  // ---- denominator (log2 domain) ----
  float v = (startT[kk] + logits[lbase * Lc + kk]) * INV_LN2;
  for (int p = 0; p < NCHUNK; ++p) {
    const float* Mp = Mws + (size_t)(b * NCHUNK + p) * 169;
    float a[13];
#pragma unroll
    for (int j = 0; j < 13; ++j) a[j] = __shfl(v, j, 64) + Mp[j * 13 + kk];
    float mx = a[0];
#pragma unroll
    for (int j = 1; j < 13; ++j) mx = fmaxf(mx, a[j]);
    float s = 0.f;
#pragma unroll
    for (int j = 0; j < 13; ++j) s += EXP2F(a[j] - mx);
    v = mx + LOG2F(s);
  }
  float x = (lane < 13) ? (v + endT[kk] * INV_LN2) : -1e30f;
  float mx = x;
#pragma unroll
  for (int off = 1; off < 16; off <<= 1) mx = fmaxf(mx, __shfl_xor(mx, off, 16));
  float sx = EXP2F(x - mx);
#pragma unroll
  for (int off = 1; off < 16; off <<= 1) sx += __shfl_xor(sx, off, 16);
  float den = (mx + LOG2F(sx)) * LN2f;   // valid on lanes 0..15

  // ---- numerator from chunk partials (lanes 0..15) ----
  float np = 0.f, cs = 0.f;
  if (lane < NCHUNK) { np = numpart[b * NCHUNK + lane]; cs = cntpart[b * NCHUNK + lane]; }
#pragma unroll
  for (int o = 1; o < 16; o <<= 1) {
    np += __shfl_xor(np, o, 16);
    cs += __shfl_xor(cs, o, 16);
  }
  if (lane == 0) {
    int lab0 = labels[lbase];
    int seqlen = mask[lbase] + (int)(cs + 0.5f);
    int lastTag = labels[lbase + seqlen - 1];
    float num = startT[lab0] + logits[lbase * Lc + lab0] + np + endT[lastTag];
    float llh = num - den;
    atomicAdd(out0, -llh * (1.0f / Bc));
  }
}

extern "C" void kernel_launch(void* const* d_in, const int* in_sizes, int n_in,
                              void* d_out, int out_size, void* d_ws, size_t ws_size,
                              hipStream_t stream) {
  const float* hs     = (const float*)d_in[0];
  const int*   amask  = (const int*)d_in[1];
  const int*   labels = (const int*)d_in[2];
  const float* W      = (const float*)d_in[3];
  const float* bias   = (const float*)d_in[4];
  const float* startT = (const float*)d_in[5];
  const float* endT   = (const float*)d_in[6];
  const float* T      = (const float*)d_in[7];

  float* out    = (float*)d_out;
  float* logits = out + 1;            // output 1 follows the scalar loss
  float* Mws    = (float*)d_ws;       // 512*169 floats = 346 KB
  float* numpart = Mws + (size_t)NBLK * 169;
  float* cntpart = numpart + NBLK;    // total ~350 KB of ws

  k_logits<<<BSc / 16, 256, 0, stream>>>(hs, W, bias, logits);
  k_chunks<<<NBLK, 256, 0, stream>>>(logits, amask, labels, T, Mws, numpart, cntpart, out);
  k_final <<<Bc, 64, 0, stream>>>(logits, amask, labels, startT, endT, Mws, numpart, cntpart, out);
}